// Round 12
// baseline (60.659 us; speedup 1.0000x reference)
//
#include <hip/hip_runtime.h>
#include <hip/hip_bf16.h>

#define N_ROWS 8192
#define DIM    128
#define NCHUNK 16                  // column chunks in sim kernel
#define CHUNKC (N_ROWS / NCHUNK)   // 512 cols per chunk
#define NTILE  (CHUNKC / 32)       // 16 tiles of 32 cols per chunk

// sqrt(2*log2(e)) : (s*a)·(s*b) = 2*log2(e)*a·b, so exp2(dot) = exp(2*sim)
#define ENSCALE 1.6986436f

typedef __attribute__((ext_vector_type(8)))  short short8;
typedef __attribute__((ext_vector_type(16))) float f32x16;

__device__ inline unsigned short f2bf(float f) {
    unsigned u = __float_as_uint(f);
    unsigned r = (u + 0x7FFFu + ((u >> 16) & 1u)) >> 16;
    return (unsigned short)r;
}
__device__ inline float bf2f(unsigned short u) {
    return __uint_as_float(((unsigned)u) << 16);
}
__device__ inline int labof(int4 v, int j) {
    return j == 0 ? v.x : j == 1 ? v.y : j == 2 ? v.z : v.w;
}

// Kernel 1: per-row L2 normalize embed -> bf16 (scaled by ENSCALE), and
// e2p[i] = exp(2*dot(en,pn)) in fp32.
__global__ __launch_bounds__(256) void norm_kernel(
    const float* __restrict__ embed, const float* __restrict__ proxy,
    short* __restrict__ enb, float* __restrict__ e2p)
{
    int wave = threadIdx.x >> 6, lane = threadIdx.x & 63;
    int row = blockIdx.x * 4 + wave;

    const float2 ev = *(const float2*)(embed + row * DIM + lane * 2);
    float ss = ev.x * ev.x + ev.y * ev.y;
#pragma unroll
    for (int m = 1; m < 64; m <<= 1) ss += __shfl_xor(ss, m, 64);
    float inv_e = 1.0f / fmaxf(sqrtf(ss), 1e-8f);
    float ex = ev.x * inv_e, ey = ev.y * inv_e;

    const float2 pv = *(const float2*)(proxy + row * DIM + lane * 2);
    float ps = pv.x * pv.x + pv.y * pv.y;
#pragma unroll
    for (int m = 1; m < 64; m <<= 1) ps += __shfl_xor(ps, m, 64);
    float inv_p = 1.0f / fmaxf(sqrtf(ps), 1e-8f);

    float dot = ex * (pv.x * inv_p) + ey * (pv.y * inv_p);
#pragma unroll
    for (int m = 1; m < 64; m <<= 1) dot += __shfl_xor(dot, m, 64);

    ushort2 st; st.x = f2bf(ex * ENSCALE); st.y = f2bf(ey * ENSCALE);
    *(ushort2*)(enb + row * DIM + lane * 2) = st;
    if (lane == 0) e2p[row] = __expf(2.0f * dot);
}

// Kernel 1b: repack enb (row-major) into MFMA fragment layout:
//   enbF[((tile*8 + kk)*64 + lane)*8 + j]
//     = enb[(tile*32 + (lane&31))*128 + kk*16 + (lane>>5)*8 + j]
// One wave per (tile,kk): 1 gather-read + 1 coalesced 16B write. This pays
// the row-gather cost ONCE (R10/R11 diagnosis: per-tile 32-line gathers at
// ~4cy/line of CU TA occupancy were the simsum bottleneck).
__global__ __launch_bounds__(256) void repack_kernel(
    const short* __restrict__ enb, short* __restrict__ enbF)
{
    int w = blockIdx.x * 4 + (threadIdx.x >> 6);   // 0..2047
    int lane = threadIdx.x & 63;
    int tile = w >> 3, kk = w & 7;
    short8 v = *(const short8*)(enb + (size_t)(tile * 32 + (lane & 31)) * DIM
                                + kk * 16 + (lane >> 5) * 8);
    *(short8*)(enbF + ((size_t)w * 64 + lane) * 8) = v;
}

// Kernel 2: fused sim-GEMM + exp + full row sum (tot only; pos separate).
// ALL loads fully coalesced from the fragment-layout enbF (2MB, L2-resident;
// same addresses shared by all 32 row-blocks -> R2-proven L2-hit path).
// No LDS, no barriers: wave owns 64 rows (rres0/rres1 from enbF tiles
// wrbase/32, wrbase/32+1), sweeps 16 column tiles; each tile = 8 coalesced
// fragment loads feeding 16 MFMAs in two independent chains.
// Operand-swapped MFMA: lane cl owns output rows wrbase+cl / wrbase+32+cl;
// acc regs span tile cols: col(reg) = (reg&3) + 4*hi + 8*(reg>>2).
__global__ __launch_bounds__(256, 3) void simsum_kernel(
    const short* __restrict__ enbF, float* __restrict__ ptot)
{
    const int tid = threadIdx.x;
    const int wave = tid >> 6;
    const int lane = tid & 63;
    const int cl = lane & 31;       // output row lane / tile col selector
    const int hi = lane >> 5;       // k-group
    const int wrbase = blockIdx.x * 256 + wave * 64;
    const int cbase0 = blockIdx.y * CHUNKC;
    const int btile0 = cbase0 >> 5;

    // register-resident A: the wave's 64 rows = fragment tiles rt0, rt0+1
    short8 rres0[8], rres1[8];
    {
        const short* f0 = enbF + ((size_t)((wrbase >> 5) * 8) * 64 + lane) * 8;
#pragma unroll
        for (int kk = 0; kk < 8; kk++) {
            rres0[kk] = *(const short8*)(f0 + kk * 512);
            rres1[kk] = *(const short8*)(f0 + 4096 + kk * 512);
        }
    }

    float tot0[4] = {0.f, 0.f, 0.f, 0.f};
    float tot1[4] = {0.f, 0.f, 0.f, 0.f};

#pragma unroll 2
    for (int t = 0; t < NTILE; t++) {
        const int cb = cbase0 + t * 32;

        // B fragments: coalesced 1KB loads from enbF
        const short* bf = enbF + ((size_t)((btile0 + t) * 8) * 64 + lane) * 8;
        short8 b[8];
#pragma unroll
        for (int kk = 0; kk < 8; kk++)
            b[kk] = *(const short8*)(bf + kk * 512);

        f32x16 c0 = {}, c1 = {};
        __builtin_amdgcn_s_setprio(1);
#pragma unroll
        for (int kk = 0; kk < 8; kk++) {
            c0 = __builtin_amdgcn_mfma_f32_32x32x16_bf16(b[kk], rres0[kk], c0, 0, 0, 0);
            c1 = __builtin_amdgcn_mfma_f32_32x32x16_bf16(b[kk], rres1[kk], c1, 0, 0, 0);
        }
        __builtin_amdgcn_s_setprio(0);

        // wave-uniform branch: only 2 of 16 tiles per wave touch the diagonal
        if (cb == wrbase || cb == wrbase + 32) {
            const bool d0_ = (cb == wrbase);
#pragma unroll
            for (int r = 0; r < 16; r++) {
                int colr = (r & 3) + 4 * hi + 8 * (r >> 2);
                float s0 = __builtin_amdgcn_exp2f(c0[r]);
                float s1 = __builtin_amdgcn_exp2f(c1[r]);
                s0 = (d0_ && colr == cl) ? 0.f : s0;
                s1 = (!d0_ && colr == cl) ? 0.f : s1;
                tot0[r & 3] += s0;
                tot1[r & 3] += s1;
            }
        } else {
#pragma unroll
            for (int r = 0; r < 16; r++) {
                tot0[r & 3] += __builtin_amdgcn_exp2f(c0[r]);
                tot1[r & 3] += __builtin_amdgcn_exp2f(c1[r]);
            }
        }
    }

    float t0 = tot0[0] + tot0[1] + tot0[2] + tot0[3];
    float t1 = tot1[0] + tot1[1] + tot1[2] + tot1[3];
    t0 += __shfl_xor(t0, 32, 64);   // merge the two k-groups (disjoint cols)
    t1 += __shfl_xor(t1, 32, 64);
    if (hi == 0) {
        ptot[blockIdx.y * N_ROWS + wrbase + cl] = t0;
        ptot[blockIdx.y * N_ROWS + wrbase + 32 + cl] = t1;
    }
}

// Kernel 3: positives + per-row loss, fused. One wave per row: int4
// ballot-scan labels, lane-parallel dot per same-label j, accumulate
// exp2; then the row's log-ratio (ptot partials read LANE-PARALLEL);
// block partial (4 rows) -> pl.
__global__ __launch_bounds__(256) void posloss_kernel(
    const short* __restrict__ enb, const int* __restrict__ label,
    const float* __restrict__ e2p, const float* __restrict__ ptot,
    float* __restrict__ pl)
{
    int wave = threadIdx.x >> 6, lane = threadIdx.x & 63;
    int row = blockIdx.x * 4 + wave;
    int mylab = label[row];

    ushort2 e2 = *(const ushort2*)(enb + (size_t)row * DIM + lane * 2);
    float ei0 = bf2f(e2.x), ei1 = bf2f(e2.y);

    // parallel partial-sum read (16 lanes, one per chunk)
    float tp = (lane < NCHUNK) ? ptot[lane * N_ROWS + row] : 0.f;

    float acc = 0.f;
#pragma unroll 1
    for (int ch = 0; ch < N_ROWS / 256; ch++) {
        int4 lv = *(const int4*)(label + ch * 256 + lane * 4);
#pragma unroll
        for (int q = 0; q < 4; q++) {
            int j = ch * 256 + lane * 4 + q;
            bool m = (labof(lv, q) == mylab) && (j != row);
            unsigned long long mask = __ballot(m);
            while (mask) {
                int jj = ch * 256 + 4 * (__ffsll(mask) - 1) + q;
                mask &= mask - 1;
                ushort2 f2 = *(const ushort2*)(enb + (size_t)jj * DIM + lane * 2);
                float d = ei0 * bf2f(f2.x) + ei1 * bf2f(f2.y);
#pragma unroll
                for (int s = 1; s < 64; s <<= 1) d += __shfl_xor(d, s, 64);
                acc += __builtin_amdgcn_exp2f(d);
            }
        }
    }

#pragma unroll
    for (int m = 1; m < 64; m <<= 1) tp += __shfl_xor(tp, m, 64);

    float e = e2p[row];
    float v = __logf((e + acc) / (e + tp));

    __shared__ float red[4];
    if (lane == 0) red[wave] = v;
    __syncthreads();
    if (threadIdx.x == 0) pl[blockIdx.x] = red[0] + red[1] + red[2] + red[3];
}

// Kernel 4: final sum of 2048 partials -> -mean
__global__ __launch_bounds__(256) void loss_final_kernel(
    const float* __restrict__ pl, float* __restrict__ out)
{
    float v = 0.f;
#pragma unroll
    for (int q = 0; q < 8; q++) v += pl[threadIdx.x * 8 + q];
#pragma unroll
    for (int m = 1; m < 64; m <<= 1) v += __shfl_xor(v, m, 64);
    __shared__ float red[4];
    int wave = threadIdx.x >> 6, lane = threadIdx.x & 63;
    if (lane == 0) red[wave] = v;
    __syncthreads();
    if (threadIdx.x == 0)
        out[0] = -(red[0] + red[1] + red[2] + red[3]) / (float)N_ROWS;
}

extern "C" void kernel_launch(void* const* d_in, const int* in_sizes, int n_in,
                              void* d_out, int out_size, void* d_ws, size_t ws_size,
                              hipStream_t stream) {
    const float* embed = (const float*)d_in[0];
    const float* proxy = (const float*)d_in[1];
    const int*   label = (const int*)d_in[2];
    float* out = (float*)d_out;

    char* ws = (char*)d_ws;
    short* enb  = (short*)ws;                                   // 2 MB
    short* enbF = enb + (size_t)N_ROWS * DIM;                   // 2 MB
    float* e2p  = (float*)(ws + 4u * N_ROWS * DIM);             // 32 KB
    float* ptot = e2p + N_ROWS;                                 // 512 KB
    float* pl   = ptot + NCHUNK * N_ROWS;                       // 8 KB

    hipLaunchKernelGGL(norm_kernel, dim3(N_ROWS / 4), dim3(256), 0, stream,
                       embed, proxy, enb, e2p);
    hipLaunchKernelGGL(repack_kernel, dim3(512), dim3(256), 0, stream,
                       enb, enbF);
    hipLaunchKernelGGL(simsum_kernel, dim3(N_ROWS / 256, NCHUNK), dim3(256), 0, stream,
                       enbF, ptot);
    hipLaunchKernelGGL(posloss_kernel, dim3(N_ROWS / 4), dim3(256), 0, stream,
                       enb, label, e2p, ptot, pl);
    hipLaunchKernelGGL(loss_final_kernel, dim3(1), dim3(256), 0, stream, pl, out);
}